// Round 1
// baseline (734.081 us; speedup 1.0000x reference)
//
#include <hip/hip_runtime.h>

constexpr int N_NODES = 100000;
constexpr int N_EDGES = 800000;
constexpr int F_DIM   = 64;

// ---------------------------------------------------------------------------
// Kernel 1: per-node in-degree counts (int atomics), 1 thread per edge.
// ---------------------------------------------------------------------------
__global__ void mp_count_kernel(const int* __restrict__ tgt,
                                int* __restrict__ counts) {
    int e = blockIdx.x * blockDim.x + threadIdx.x;
    if (e < N_EDGES) {
        atomicAdd(&counts[tgt[e]], 1);
    }
}

// ---------------------------------------------------------------------------
// Kernel 2: scatter-add messages. 16 threads per edge; each thread loads one
// float4 (coalesced 256B per edge across 16 lanes) and does 4 f32 atomics.
// unsafeAtomicAdd -> native global_atomic_add_f32 (no CAS loop).
// ---------------------------------------------------------------------------
__global__ void mp_scatter_kernel(const float* __restrict__ x,
                                  const int* __restrict__ src,
                                  const int* __restrict__ tgt,
                                  float* __restrict__ out) {
    int gid = blockIdx.x * blockDim.x + threadIdx.x;
    int e = gid >> 4;          // edge index
    int q = gid & 15;          // float4 quad within the 64-dim feature
    if (e >= N_EDGES) return;
    int s = src[e];
    int t = tgt[e];
    const float4 v = *reinterpret_cast<const float4*>(
        x + (size_t)s * F_DIM + q * 4);
    float* o = out + (size_t)t * F_DIM + q * 4;
    unsafeAtomicAdd(o + 0, v.x);
    unsafeAtomicAdd(o + 1, v.y);
    unsafeAtomicAdd(o + 2, v.z);
    unsafeAtomicAdd(o + 3, v.w);
}

// ---------------------------------------------------------------------------
// Kernel 3: divide sums by max(count, 1). 16 threads per node, float4 each.
// ---------------------------------------------------------------------------
__global__ void mp_div_kernel(float* __restrict__ out,
                              const int* __restrict__ counts) {
    int gid = blockIdx.x * blockDim.x + threadIdx.x;
    int i = gid >> 4;          // node index
    int q = gid & 15;
    if (i >= N_NODES) return;
    float inv = 1.0f / fmaxf((float)counts[i], 1.0f);
    float4* o = reinterpret_cast<float4*>(out + (size_t)i * F_DIM + q * 4);
    float4 v = *o;
    v.x *= inv; v.y *= inv; v.z *= inv; v.w *= inv;
    *o = v;
}

extern "C" void kernel_launch(void* const* d_in, const int* in_sizes, int n_in,
                              void* d_out, int out_size, void* d_ws, size_t ws_size,
                              hipStream_t stream) {
    const float* x   = (const float*)d_in[0];
    const int*   src = (const int*)d_in[1];
    const int*   tgt = (const int*)d_in[2];
    float* out = (float*)d_out;
    int*   counts = (int*)d_ws;   // N_NODES ints = 400 KB scratch

    // Zero accumulators every call (harness does not re-poison between replays).
    hipMemsetAsync(out, 0, (size_t)N_NODES * F_DIM * sizeof(float), stream);
    hipMemsetAsync(counts, 0, (size_t)N_NODES * sizeof(int), stream);

    {
        int threads = 256;
        int blocks = (N_EDGES + threads - 1) / threads;
        mp_count_kernel<<<blocks, threads, 0, stream>>>(tgt, counts);
    }
    {
        int threads = 256;
        long long total = (long long)N_EDGES * 16;
        int blocks = (int)((total + threads - 1) / threads);
        mp_scatter_kernel<<<blocks, threads, 0, stream>>>(x, src, tgt, out);
    }
    {
        int threads = 256;
        long long total = (long long)N_NODES * 16;
        int blocks = (int)((total + threads - 1) / threads);
        mp_div_kernel<<<blocks, threads, 0, stream>>>(out, counts);
    }
}

// Round 2
// 235.005 us; speedup vs baseline: 3.1237x; 3.1237x over previous
//
#include <hip/hip_runtime.h>

constexpr int N_NODES = 100000;
constexpr int N_EDGES = 800000;
constexpr int F_DIM   = 64;

// ===========================================================================
// CSR-build + gather implementation (no f32 atomics).
//   ws layout: offsets[N+1] | cursor[N] | counts[N] | edge_src[E]
// ===========================================================================

// --- Kernel 1: in-degree counts ------------------------------------------
__global__ void mp_count_kernel(const int* __restrict__ tgt,
                                int* __restrict__ counts) {
    int e = blockIdx.x * blockDim.x + threadIdx.x;
    if (e < N_EDGES) atomicAdd(&counts[tgt[e]], 1);
}

// --- Kernel 2: single-workgroup exclusive scan (1024 thr = 16 waves) ------
__global__ void __launch_bounds__(1024)
mp_scan_kernel(const int* __restrict__ counts, int* __restrict__ offsets) {
    __shared__ int ws_incl[16];
    __shared__ int s_total;
    const int tid  = threadIdx.x;
    const int lane = tid & 63;
    const int wid  = tid >> 6;
    int carry = 0;
    for (int base = 0; base < N_NODES; base += 1024) {
        int i = base + tid;
        int v = (i < N_NODES) ? counts[i] : 0;
        // inclusive wave scan (shfl_up)
        int sc = v;
        #pragma unroll
        for (int d = 1; d < 64; d <<= 1) {
            int up = __shfl_up(sc, d, 64);
            if (lane >= d) sc += up;
        }
        if (lane == 63) ws_incl[wid] = sc;
        __syncthreads();
        if (tid < 16) {
            int w = ws_incl[tid];
            int scw = w;
            #pragma unroll
            for (int d = 1; d < 16; d <<= 1) {
                int up = __shfl_up(scw, d, 16);
                if (tid >= d) scw += up;
            }
            ws_incl[tid] = scw - w;            // exclusive wave offset
            if (tid == 15) s_total = scw;      // chunk total
        }
        __syncthreads();
        if (i < N_NODES) offsets[i] = carry + ws_incl[wid] + (sc - v);
        carry += s_total;
        __syncthreads();                       // protect ws_incl/s_total reuse
    }
    if (tid == 0) offsets[N_NODES] = carry;
}

// --- Kernel 3: bucket-fill edge sources (int atomics on cursors) ----------
__global__ void mp_fill_kernel(const int* __restrict__ src,
                               const int* __restrict__ tgt,
                               int* __restrict__ cursor,
                               int* __restrict__ edge_src) {
    int e = blockIdx.x * blockDim.x + threadIdx.x;
    if (e < N_EDGES) {
        int p = atomicAdd(&cursor[tgt[e]], 1);
        edge_src[p] = src[e];
    }
}

// --- Kernel 4: gather-mean. One wave per node, lane = feature. ------------
__global__ void __launch_bounds__(256)
mp_gather_kernel(const float* __restrict__ x,
                 const int* __restrict__ offsets,
                 const int* __restrict__ edge_src,
                 float* __restrict__ out) {
    int node = blockIdx.x * 4 + (threadIdx.x >> 6);
    int lane = threadIdx.x & 63;
    if (node >= N_NODES) return;
    int beg = offsets[node];
    int end = offsets[node + 1];
    float acc0 = 0.f, acc1 = 0.f;
    int j = beg;
    for (; j + 1 < end; j += 2) {      // 2-edge unroll: overlap idx loads
        int s0 = edge_src[j];
        int s1 = edge_src[j + 1];
        acc0 += x[(size_t)s0 * F_DIM + lane];
        acc1 += x[(size_t)s1 * F_DIM + lane];
    }
    if (j < end) acc0 += x[(size_t)edge_src[j] * F_DIM + lane];
    int deg = end - beg;
    float inv = (deg > 0) ? 1.0f / (float)deg : 0.0f;
    out[(size_t)node * F_DIM + lane] = (acc0 + acc1) * inv;
}

// ===========================================================================
// Fallback (round-0 path) if workspace is too small — safety net only.
// ===========================================================================
__global__ void mp_scatter_kernel(const float* __restrict__ x,
                                  const int* __restrict__ src,
                                  const int* __restrict__ tgt,
                                  float* __restrict__ out) {
    int gid = blockIdx.x * blockDim.x + threadIdx.x;
    int e = gid >> 4;
    int q = gid & 15;
    if (e >= N_EDGES) return;
    int s = src[e];
    int t = tgt[e];
    const float4 v = *reinterpret_cast<const float4*>(x + (size_t)s * F_DIM + q * 4);
    float* o = out + (size_t)t * F_DIM + q * 4;
    unsafeAtomicAdd(o + 0, v.x);
    unsafeAtomicAdd(o + 1, v.y);
    unsafeAtomicAdd(o + 2, v.z);
    unsafeAtomicAdd(o + 3, v.w);
}

__global__ void mp_div_kernel(float* __restrict__ out,
                              const int* __restrict__ counts) {
    int gid = blockIdx.x * blockDim.x + threadIdx.x;
    int i = gid >> 4;
    int q = gid & 15;
    if (i >= N_NODES) return;
    float inv = 1.0f / fmaxf((float)counts[i], 1.0f);
    float4* o = reinterpret_cast<float4*>(out + (size_t)i * F_DIM + q * 4);
    float4 v = *o;
    v.x *= inv; v.y *= inv; v.z *= inv; v.w *= inv;
    *o = v;
}

extern "C" void kernel_launch(void* const* d_in, const int* in_sizes, int n_in,
                              void* d_out, int out_size, void* d_ws, size_t ws_size,
                              hipStream_t stream) {
    const float* x   = (const float*)d_in[0];
    const int*   src = (const int*)d_in[1];
    const int*   tgt = (const int*)d_in[2];
    float* out = (float*)d_out;

    const size_t need = (size_t)(N_NODES + 1 + N_NODES + N_NODES + N_EDGES) * sizeof(int);

    if (ws_size >= need) {
        int* offsets  = (int*)d_ws;                 // N+1
        int* cursor   = offsets + (N_NODES + 1);    // N
        int* counts   = cursor + N_NODES;           // N
        int* edge_src = counts + N_NODES;           // E

        hipMemsetAsync(counts, 0, (size_t)N_NODES * sizeof(int), stream);

        int threads = 256;
        int eblocks = (N_EDGES + threads - 1) / threads;
        mp_count_kernel<<<eblocks, threads, 0, stream>>>(tgt, counts);
        mp_scan_kernel<<<1, 1024, 0, stream>>>(counts, offsets);
        hipMemcpyAsync(cursor, offsets, (size_t)N_NODES * sizeof(int),
                       hipMemcpyDeviceToDevice, stream);
        mp_fill_kernel<<<eblocks, threads, 0, stream>>>(src, tgt, cursor, edge_src);
        int nblocks = (N_NODES + 3) / 4;            // 4 nodes (waves) per block
        mp_gather_kernel<<<nblocks, threads, 0, stream>>>(x, offsets, edge_src, out);
    } else {
        // Fallback: atomic scatter path (round-0).
        int* counts = (int*)d_ws;
        hipMemsetAsync(out, 0, (size_t)N_NODES * F_DIM * sizeof(float), stream);
        hipMemsetAsync(counts, 0, (size_t)N_NODES * sizeof(int), stream);
        int threads = 256;
        int eblocks = (N_EDGES + threads - 1) / threads;
        mp_count_kernel<<<eblocks, threads, 0, stream>>>(tgt, counts);
        long long total = (long long)N_EDGES * 16;
        int sblocks = (int)((total + threads - 1) / threads);
        mp_scatter_kernel<<<sblocks, threads, 0, stream>>>(x, src, tgt, out);
        long long dtotal = (long long)N_NODES * 16;
        int dblocks = (int)((dtotal + threads - 1) / threads);
        mp_div_kernel<<<dblocks, threads, 0, stream>>>(out, counts);
    }
}

// Round 3
// 159.084 us; speedup vs baseline: 4.6144x; 1.4772x over previous
//
#include <hip/hip_runtime.h>

constexpr int N_NODES = 100000;
constexpr int N_EDGES = 800000;
constexpr int F_DIM   = 64;
constexpr int SCAN_BLK = 256;
constexpr int N_SCAN_BLOCKS = (N_NODES + SCAN_BLK - 1) / SCAN_BLK;   // 391

// ===========================================================================
// CSR-build + gather implementation (no f32 atomics).
//   ws layout: offsets[N+1] | cursor[N] | counts[N] | edge_src[E] | blockSums[NB]
// ===========================================================================

// --- Kernel 1: in-degree counts ------------------------------------------
__global__ void mp_count_kernel(const int* __restrict__ tgt,
                                int* __restrict__ counts) {
    int e = blockIdx.x * blockDim.x + threadIdx.x;
    if (e < N_EDGES) atomicAdd(&counts[tgt[e]], 1);
}

// --- Kernel 2a: per-block sums of counts ----------------------------------
__global__ void __launch_bounds__(SCAN_BLK)
mp_scan_blocksums(const int* __restrict__ counts, int* __restrict__ blockSums) {
    const int tid  = threadIdx.x;
    const int lane = tid & 63;
    const int wid  = tid >> 6;
    int i = blockIdx.x * SCAN_BLK + tid;
    int v = (i < N_NODES) ? counts[i] : 0;
    #pragma unroll
    for (int d = 32; d > 0; d >>= 1) v += __shfl_down(v, d, 64);
    __shared__ int ws[SCAN_BLK / 64];
    if (lane == 0) ws[wid] = v;
    __syncthreads();
    if (tid == 0) blockSums[blockIdx.x] = ws[0] + ws[1] + ws[2] + ws[3];
}

// --- Kernel 2b: exclusive scan of the 391 block sums (one block) ----------
__global__ void __launch_bounds__(512)
mp_scan_level1(int* __restrict__ blockSums) {
    const int tid  = threadIdx.x;
    const int lane = tid & 63;
    const int wid  = tid >> 6;
    int v = (tid < N_SCAN_BLOCKS) ? blockSums[tid] : 0;
    int sc = v;
    #pragma unroll
    for (int d = 1; d < 64; d <<= 1) {
        int up = __shfl_up(sc, d, 64);
        if (lane >= d) sc += up;
    }
    __shared__ int ws[8];
    if (lane == 63) ws[wid] = sc;
    __syncthreads();
    if (tid < 8) {
        int w = ws[tid];
        int scw = w;
        #pragma unroll
        for (int d = 1; d < 8; d <<= 1) {
            int up = __shfl_up(scw, d, 8);
            if (tid >= d) scw += up;
        }
        ws[tid] = scw - w;          // exclusive wave offset
    }
    __syncthreads();
    if (tid < N_SCAN_BLOCKS) blockSums[tid] = ws[wid] + (sc - v);
}

// --- Kernel 2c: downsweep — write offsets AND cursor ----------------------
__global__ void __launch_bounds__(SCAN_BLK)
mp_scan_downsweep(const int* __restrict__ counts,
                  const int* __restrict__ blockSums,
                  int* __restrict__ offsets,
                  int* __restrict__ cursor) {
    const int tid  = threadIdx.x;
    const int lane = tid & 63;
    const int wid  = tid >> 6;
    int i = blockIdx.x * SCAN_BLK + tid;
    int v = (i < N_NODES) ? counts[i] : 0;
    int sc = v;
    #pragma unroll
    for (int d = 1; d < 64; d <<= 1) {
        int up = __shfl_up(sc, d, 64);
        if (lane >= d) sc += up;
    }
    __shared__ int ws[SCAN_BLK / 64];
    if (lane == 63) ws[wid] = sc;
    __syncthreads();
    int waveOff = 0;
    #pragma unroll
    for (int w = 0; w < SCAN_BLK / 64; ++w)
        if (w < wid) waveOff += ws[w];
    int off = blockSums[blockIdx.x] + waveOff + (sc - v);
    if (i < N_NODES) {
        offsets[i] = off;
        cursor[i]  = off;
        if (i == N_NODES - 1) offsets[N_NODES] = off + v;
    }
}

// --- Kernel 3: bucket-fill edge sources (int atomics on cursors) ----------
__global__ void mp_fill_kernel(const int* __restrict__ src,
                               const int* __restrict__ tgt,
                               int* __restrict__ cursor,
                               int* __restrict__ edge_src) {
    int e = blockIdx.x * blockDim.x + threadIdx.x;
    if (e < N_EDGES) {
        int p = atomicAdd(&cursor[tgt[e]], 1);
        edge_src[p] = src[e];
    }
}

// --- Kernel 4: gather-mean. One wave per node, lane = feature. ------------
__global__ void __launch_bounds__(256)
mp_gather_kernel(const float* __restrict__ x,
                 const int* __restrict__ offsets,
                 const int* __restrict__ edge_src,
                 float* __restrict__ out) {
    int node = blockIdx.x * 4 + (threadIdx.x >> 6);
    int lane = threadIdx.x & 63;
    if (node >= N_NODES) return;
    int beg = offsets[node];
    int end = offsets[node + 1];
    float acc0 = 0.f, acc1 = 0.f;
    int j = beg;
    for (; j + 1 < end; j += 2) {      // 2-edge unroll: overlap idx loads
        int s0 = edge_src[j];
        int s1 = edge_src[j + 1];
        acc0 += x[(size_t)s0 * F_DIM + lane];
        acc1 += x[(size_t)s1 * F_DIM + lane];
    }
    if (j < end) acc0 += x[(size_t)edge_src[j] * F_DIM + lane];
    int deg = end - beg;
    float inv = (deg > 0) ? 1.0f / (float)deg : 0.0f;
    out[(size_t)node * F_DIM + lane] = (acc0 + acc1) * inv;
}

// ===========================================================================
// Fallback (round-0 path) if workspace is too small — safety net only.
// ===========================================================================
__global__ void mp_scatter_kernel(const float* __restrict__ x,
                                  const int* __restrict__ src,
                                  const int* __restrict__ tgt,
                                  float* __restrict__ out) {
    int gid = blockIdx.x * blockDim.x + threadIdx.x;
    int e = gid >> 4;
    int q = gid & 15;
    if (e >= N_EDGES) return;
    int s = src[e];
    int t = tgt[e];
    const float4 v = *reinterpret_cast<const float4*>(x + (size_t)s * F_DIM + q * 4);
    float* o = out + (size_t)t * F_DIM + q * 4;
    unsafeAtomicAdd(o + 0, v.x);
    unsafeAtomicAdd(o + 1, v.y);
    unsafeAtomicAdd(o + 2, v.z);
    unsafeAtomicAdd(o + 3, v.w);
}

__global__ void mp_div_kernel(float* __restrict__ out,
                              const int* __restrict__ counts) {
    int gid = blockIdx.x * blockDim.x + threadIdx.x;
    int i = gid >> 4;
    int q = gid & 15;
    if (i >= N_NODES) return;
    float inv = 1.0f / fmaxf((float)counts[i], 1.0f);
    float4* o = reinterpret_cast<float4*>(out + (size_t)i * F_DIM + q * 4);
    float4 v = *o;
    v.x *= inv; v.y *= inv; v.z *= inv; v.w *= inv;
    *o = v;
}

extern "C" void kernel_launch(void* const* d_in, const int* in_sizes, int n_in,
                              void* d_out, int out_size, void* d_ws, size_t ws_size,
                              hipStream_t stream) {
    const float* x   = (const float*)d_in[0];
    const int*   src = (const int*)d_in[1];
    const int*   tgt = (const int*)d_in[2];
    float* out = (float*)d_out;

    const size_t need = (size_t)(N_NODES + 1 + N_NODES + N_NODES + N_EDGES
                                 + N_SCAN_BLOCKS) * sizeof(int);

    if (ws_size >= need) {
        int* offsets   = (int*)d_ws;                  // N+1
        int* cursor    = offsets + (N_NODES + 1);     // N
        int* counts    = cursor + N_NODES;            // N
        int* edge_src  = counts + N_NODES;            // E
        int* blockSums = edge_src + N_EDGES;          // NB

        hipMemsetAsync(counts, 0, (size_t)N_NODES * sizeof(int), stream);

        int threads = 256;
        int eblocks = (N_EDGES + threads - 1) / threads;
        mp_count_kernel<<<eblocks, threads, 0, stream>>>(tgt, counts);
        mp_scan_blocksums<<<N_SCAN_BLOCKS, SCAN_BLK, 0, stream>>>(counts, blockSums);
        mp_scan_level1<<<1, 512, 0, stream>>>(blockSums);
        mp_scan_downsweep<<<N_SCAN_BLOCKS, SCAN_BLK, 0, stream>>>(counts, blockSums,
                                                                  offsets, cursor);
        mp_fill_kernel<<<eblocks, threads, 0, stream>>>(src, tgt, cursor, edge_src);
        int nblocks = (N_NODES + 3) / 4;              // 4 nodes (waves) per block
        mp_gather_kernel<<<nblocks, threads, 0, stream>>>(x, offsets, edge_src, out);
    } else {
        // Fallback: atomic scatter path (round-0).
        int* counts = (int*)d_ws;
        hipMemsetAsync(out, 0, (size_t)N_NODES * F_DIM * sizeof(float), stream);
        hipMemsetAsync(counts, 0, (size_t)N_NODES * sizeof(int), stream);
        int threads = 256;
        int eblocks = (N_EDGES + threads - 1) / threads;
        mp_count_kernel<<<eblocks, threads, 0, stream>>>(tgt, counts);
        long long total = (long long)N_EDGES * 16;
        int sblocks = (int)((total + threads - 1) / threads);
        mp_scatter_kernel<<<sblocks, threads, 0, stream>>>(x, src, tgt, out);
        long long dtotal = (long long)N_NODES * 16;
        int dblocks = (int)((dtotal + threads - 1) / threads);
        mp_div_kernel<<<dblocks, threads, 0, stream>>>(out, counts);
    }
}

// Round 4
// 137.091 us; speedup vs baseline: 5.3547x; 1.1604x over previous
//
#include <hip/hip_runtime.h>

constexpr int N_NODES = 100000;
constexpr int N_EDGES = 800000;
constexpr int F_DIM   = 64;
constexpr int SCAN_BLK = 256;
constexpr int N_SCAN_BLOCKS = (N_NODES + SCAN_BLK - 1) / SCAN_BLK;   // 391

// ===========================================================================
// CSR-build + gather implementation (no f32 atomics).
//   ws layout: offsets[N+1] | cursor[N] | counts[N] | edge_src[E] | blockSums[NB]
// NOTE: gather reads up to 7 ints past edge_src[E-1]; those land inside
// blockSums[] (valid memory) and are masked out of the sum.
// ===========================================================================

// --- Kernel 1: in-degree counts ------------------------------------------
__global__ void mp_count_kernel(const int* __restrict__ tgt,
                                int* __restrict__ counts) {
    int e = blockIdx.x * blockDim.x + threadIdx.x;
    if (e < N_EDGES) atomicAdd(&counts[tgt[e]], 1);
}

// --- Kernel 2a: per-block sums of counts ----------------------------------
__global__ void __launch_bounds__(SCAN_BLK)
mp_scan_blocksums(const int* __restrict__ counts, int* __restrict__ blockSums) {
    const int tid  = threadIdx.x;
    const int lane = tid & 63;
    const int wid  = tid >> 6;
    int i = blockIdx.x * SCAN_BLK + tid;
    int v = (i < N_NODES) ? counts[i] : 0;
    #pragma unroll
    for (int d = 32; d > 0; d >>= 1) v += __shfl_down(v, d, 64);
    __shared__ int ws[SCAN_BLK / 64];
    if (lane == 0) ws[wid] = v;
    __syncthreads();
    if (tid == 0) blockSums[blockIdx.x] = ws[0] + ws[1] + ws[2] + ws[3];
}

// --- Kernel 2b: exclusive scan of the 391 block sums (one block) ----------
__global__ void __launch_bounds__(512)
mp_scan_level1(int* __restrict__ blockSums) {
    const int tid  = threadIdx.x;
    const int lane = tid & 63;
    const int wid  = tid >> 6;
    int v = (tid < N_SCAN_BLOCKS) ? blockSums[tid] : 0;
    int sc = v;
    #pragma unroll
    for (int d = 1; d < 64; d <<= 1) {
        int up = __shfl_up(sc, d, 64);
        if (lane >= d) sc += up;
    }
    __shared__ int ws[8];
    if (lane == 63) ws[wid] = sc;
    __syncthreads();
    if (tid < 8) {
        int w = ws[tid];
        int scw = w;
        #pragma unroll
        for (int d = 1; d < 8; d <<= 1) {
            int up = __shfl_up(scw, d, 8);
            if (tid >= d) scw += up;
        }
        ws[tid] = scw - w;          // exclusive wave offset
    }
    __syncthreads();
    if (tid < N_SCAN_BLOCKS) blockSums[tid] = ws[wid] + (sc - v);
}

// --- Kernel 2c: downsweep — write offsets AND cursor ----------------------
__global__ void __launch_bounds__(SCAN_BLK)
mp_scan_downsweep(const int* __restrict__ counts,
                  const int* __restrict__ blockSums,
                  int* __restrict__ offsets,
                  int* __restrict__ cursor) {
    const int tid  = threadIdx.x;
    const int lane = tid & 63;
    const int wid  = tid >> 6;
    int i = blockIdx.x * SCAN_BLK + tid;
    int v = (i < N_NODES) ? counts[i] : 0;
    int sc = v;
    #pragma unroll
    for (int d = 1; d < 64; d <<= 1) {
        int up = __shfl_up(sc, d, 64);
        if (lane >= d) sc += up;
    }
    __shared__ int ws[SCAN_BLK / 64];
    if (lane == 63) ws[wid] = sc;
    __syncthreads();
    int waveOff = 0;
    #pragma unroll
    for (int w = 0; w < SCAN_BLK / 64; ++w)
        if (w < wid) waveOff += ws[w];
    int off = blockSums[blockIdx.x] + waveOff + (sc - v);
    if (i < N_NODES) {
        offsets[i] = off;
        cursor[i]  = off;
        if (i == N_NODES - 1) offsets[N_NODES] = off + v;
    }
}

// --- Kernel 3: bucket-fill edge sources (int atomics on cursors) ----------
__global__ void mp_fill_kernel(const int* __restrict__ src,
                               const int* __restrict__ tgt,
                               int* __restrict__ cursor,
                               int* __restrict__ edge_src) {
    int e = blockIdx.x * blockDim.x + threadIdx.x;
    if (e < N_EDGES) {
        int p = atomicAdd(&cursor[tgt[e]], 1);
        edge_src[p] = src[e];
    }
}

// --- Kernel 4: gather-mean. One wave per node, lane = feature. ------------
// Scalarized control: node id via readfirstlane so beg/end and the edge
// indices become s_loads; 8 independent x-row loads in flight per group.
__global__ void __launch_bounds__(256)
mp_gather_kernel(const float* __restrict__ x,
                 const int* __restrict__ offsets,
                 const int* __restrict__ edge_src,
                 float* __restrict__ out) {
    const int wid  = threadIdx.x >> 6;
    const int lane = threadIdx.x & 63;
    const int node = __builtin_amdgcn_readfirstlane(blockIdx.x * 4 + wid);
    if (node >= N_NODES) return;
    const int beg = offsets[node];
    const int end = offsets[node + 1];
    float acc = 0.f;
    for (int j = beg; j < end; j += 8) {
        // Unconditional scalar index loads (≤7 past end lands in blockSums —
        // valid memory, masked below).
        int s0 = edge_src[j + 0];
        int s1 = edge_src[j + 1];
        int s2 = edge_src[j + 2];
        int s3 = edge_src[j + 3];
        int s4 = edge_src[j + 4];
        int s5 = edge_src[j + 5];
        int s6 = edge_src[j + 6];
        int s7 = edge_src[j + 7];
        const bool b1 = j + 1 < end, b2 = j + 2 < end, b3 = j + 3 < end;
        const bool b4 = j + 4 < end, b5 = j + 5 < end, b6 = j + 6 < end;
        const bool b7 = j + 7 < end;
        // Clamp garbage indices to s0 (row already being fetched -> L1 hit).
        s1 = b1 ? s1 : s0;  s2 = b2 ? s2 : s0;  s3 = b3 ? s3 : s0;
        s4 = b4 ? s4 : s0;  s5 = b5 ? s5 : s0;  s6 = b6 ? s6 : s0;
        s7 = b7 ? s7 : s0;
        // 8 independent row loads (SGPR base + lane offset).
        float a0 = x[(size_t)s0 * F_DIM + lane];
        float a1 = x[(size_t)s1 * F_DIM + lane];
        float a2 = x[(size_t)s2 * F_DIM + lane];
        float a3 = x[(size_t)s3 * F_DIM + lane];
        float a4 = x[(size_t)s4 * F_DIM + lane];
        float a5 = x[(size_t)s5 * F_DIM + lane];
        float a6 = x[(size_t)s6 * F_DIM + lane];
        float a7 = x[(size_t)s7 * F_DIM + lane];
        float t0 = a0 + (b1 ? a1 : 0.f);
        float t1 = (b2 ? a2 : 0.f) + (b3 ? a3 : 0.f);
        float t2 = (b4 ? a4 : 0.f) + (b5 ? a5 : 0.f);
        float t3 = (b6 ? a6 : 0.f) + (b7 ? a7 : 0.f);
        acc += (t0 + t1) + (t2 + t3);
    }
    const int deg = end - beg;
    const float inv = (deg > 0) ? 1.0f / (float)deg : 0.0f;
    out[(size_t)node * F_DIM + lane] = acc * inv;
}

// ===========================================================================
// Fallback (round-0 path) if workspace is too small — safety net only.
// ===========================================================================
__global__ void mp_scatter_kernel(const float* __restrict__ x,
                                  const int* __restrict__ src,
                                  const int* __restrict__ tgt,
                                  float* __restrict__ out) {
    int gid = blockIdx.x * blockDim.x + threadIdx.x;
    int e = gid >> 4;
    int q = gid & 15;
    if (e >= N_EDGES) return;
    int s = src[e];
    int t = tgt[e];
    const float4 v = *reinterpret_cast<const float4*>(x + (size_t)s * F_DIM + q * 4);
    float* o = out + (size_t)t * F_DIM + q * 4;
    unsafeAtomicAdd(o + 0, v.x);
    unsafeAtomicAdd(o + 1, v.y);
    unsafeAtomicAdd(o + 2, v.z);
    unsafeAtomicAdd(o + 3, v.w);
}

__global__ void mp_div_kernel(float* __restrict__ out,
                              const int* __restrict__ counts) {
    int gid = blockIdx.x * blockDim.x + threadIdx.x;
    int i = gid >> 4;
    int q = gid & 15;
    if (i >= N_NODES) return;
    float inv = 1.0f / fmaxf((float)counts[i], 1.0f);
    float4* o = reinterpret_cast<float4*>(out + (size_t)i * F_DIM + q * 4);
    float4 v = *o;
    v.x *= inv; v.y *= inv; v.z *= inv; v.w *= inv;
    *o = v;
}

extern "C" void kernel_launch(void* const* d_in, const int* in_sizes, int n_in,
                              void* d_out, int out_size, void* d_ws, size_t ws_size,
                              hipStream_t stream) {
    const float* x   = (const float*)d_in[0];
    const int*   src = (const int*)d_in[1];
    const int*   tgt = (const int*)d_in[2];
    float* out = (float*)d_out;

    const size_t need = (size_t)(N_NODES + 1 + N_NODES + N_NODES + N_EDGES
                                 + N_SCAN_BLOCKS) * sizeof(int);

    if (ws_size >= need) {
        int* offsets   = (int*)d_ws;                  // N+1
        int* cursor    = offsets + (N_NODES + 1);     // N
        int* counts    = cursor + N_NODES;            // N
        int* edge_src  = counts + N_NODES;            // E
        int* blockSums = edge_src + N_EDGES;          // NB

        hipMemsetAsync(counts, 0, (size_t)N_NODES * sizeof(int), stream);

        int threads = 256;
        int eblocks = (N_EDGES + threads - 1) / threads;
        mp_count_kernel<<<eblocks, threads, 0, stream>>>(tgt, counts);
        mp_scan_blocksums<<<N_SCAN_BLOCKS, SCAN_BLK, 0, stream>>>(counts, blockSums);
        mp_scan_level1<<<1, 512, 0, stream>>>(blockSums);
        mp_scan_downsweep<<<N_SCAN_BLOCKS, SCAN_BLK, 0, stream>>>(counts, blockSums,
                                                                  offsets, cursor);
        mp_fill_kernel<<<eblocks, threads, 0, stream>>>(src, tgt, cursor, edge_src);
        int nblocks = (N_NODES + 3) / 4;              // 4 nodes (waves) per block
        mp_gather_kernel<<<nblocks, threads, 0, stream>>>(x, offsets, edge_src, out);
    } else {
        // Fallback: atomic scatter path (round-0).
        int* counts = (int*)d_ws;
        hipMemsetAsync(out, 0, (size_t)N_NODES * F_DIM * sizeof(float), stream);
        hipMemsetAsync(counts, 0, (size_t)N_NODES * sizeof(int), stream);
        int threads = 256;
        int eblocks = (N_EDGES + threads - 1) / threads;
        mp_count_kernel<<<eblocks, threads, 0, stream>>>(tgt, counts);
        long long total = (long long)N_EDGES * 16;
        int sblocks = (int)((total + threads - 1) / threads);
        mp_scatter_kernel<<<sblocks, threads, 0, stream>>>(x, src, tgt, out);
        long long dtotal = (long long)N_NODES * 16;
        int dblocks = (int)((dtotal + threads - 1) / threads);
        mp_div_kernel<<<dblocks, threads, 0, stream>>>(out, counts);
    }
}

// Round 5
// 123.069 us; speedup vs baseline: 5.9648x; 1.1139x over previous
//
#include <hip/hip_runtime.h>

constexpr int N_NODES = 100000;
constexpr int N_EDGES = 800000;
constexpr int F_DIM   = 64;
constexpr int SCAN_BLK = 256;
constexpr int N_SCAN_BLOCKS = (N_NODES + SCAN_BLK - 1) / SCAN_BLK;   // 391

// XCD partitioning for the scatter phases.
constexpr int NXCD = 8;
constexpr int NODES_PER_XCD = N_NODES / NXCD;          // 12500
constexpr int FILL_CHUNKS = 128;                       // grid = 1024 blocks
constexpr int EDGES_PER_CHUNK = N_EDGES / FILL_CHUNKS; // 6250

// ===========================================================================
// CSR-build + gather implementation (no f32 atomics).
//   ws layout: offsets[N+1] | cursor[N] | counts[N] | edge_src[E] | blockSums[NB]
// NOTE: gather reads up to 7 ints past edge_src[E-1]; those land inside
// blockSums[] (valid memory) and are masked out of the sum.
//
// count/fill are XCD-partitioned: block b (heuristically on XCD b%8) filters
// edges to tgt-range [(b%8)*12500, +12500) so all atomics and scattered
// stores from one XCD hit a private region of cursor/counts/edge_src —
// avoids cross-XCD L2 line ping-pong (round-4 showed 16x write amplification).
// Mapping being wrong only costs speed, not correctness.
// ===========================================================================

// --- Kernel 1: in-degree counts (XCD-partitioned) -------------------------
__global__ void __launch_bounds__(256)
mp_count_kernel(const int* __restrict__ tgt, int* __restrict__ counts) {
    const int xcd   = blockIdx.x & (NXCD - 1);
    const int chunk = blockIdx.x >> 3;
    const int lo = xcd * NODES_PER_XCD;
    const int hi = lo + NODES_PER_XCD;
    const int base = chunk * EDGES_PER_CHUNK;
    const int endc = base + EDGES_PER_CHUNK;
    for (int e = base + threadIdx.x; e < endc; e += 256) {
        int t = tgt[e];
        if (t >= lo && t < hi) atomicAdd(&counts[t], 1);
    }
}

// --- Kernel 2a: per-block sums of counts ----------------------------------
__global__ void __launch_bounds__(SCAN_BLK)
mp_scan_blocksums(const int* __restrict__ counts, int* __restrict__ blockSums) {
    const int tid  = threadIdx.x;
    const int lane = tid & 63;
    const int wid  = tid >> 6;
    int i = blockIdx.x * SCAN_BLK + tid;
    int v = (i < N_NODES) ? counts[i] : 0;
    #pragma unroll
    for (int d = 32; d > 0; d >>= 1) v += __shfl_down(v, d, 64);
    __shared__ int ws[SCAN_BLK / 64];
    if (lane == 0) ws[wid] = v;
    __syncthreads();
    if (tid == 0) blockSums[blockIdx.x] = ws[0] + ws[1] + ws[2] + ws[3];
}

// --- Kernel 2b: exclusive scan of the 391 block sums (one block) ----------
__global__ void __launch_bounds__(512)
mp_scan_level1(int* __restrict__ blockSums) {
    const int tid  = threadIdx.x;
    const int lane = tid & 63;
    const int wid  = tid >> 6;
    int v = (tid < N_SCAN_BLOCKS) ? blockSums[tid] : 0;
    int sc = v;
    #pragma unroll
    for (int d = 1; d < 64; d <<= 1) {
        int up = __shfl_up(sc, d, 64);
        if (lane >= d) sc += up;
    }
    __shared__ int ws[8];
    if (lane == 63) ws[wid] = sc;
    __syncthreads();
    if (tid < 8) {
        int w = ws[tid];
        int scw = w;
        #pragma unroll
        for (int d = 1; d < 8; d <<= 1) {
            int up = __shfl_up(scw, d, 8);
            if (tid >= d) scw += up;
        }
        ws[tid] = scw - w;          // exclusive wave offset
    }
    __syncthreads();
    if (tid < N_SCAN_BLOCKS) blockSums[tid] = ws[wid] + (sc - v);
}

// --- Kernel 2c: downsweep — write offsets AND cursor ----------------------
__global__ void __launch_bounds__(SCAN_BLK)
mp_scan_downsweep(const int* __restrict__ counts,
                  const int* __restrict__ blockSums,
                  int* __restrict__ offsets,
                  int* __restrict__ cursor) {
    const int tid  = threadIdx.x;
    const int lane = tid & 63;
    const int wid  = tid >> 6;
    int i = blockIdx.x * SCAN_BLK + tid;
    int v = (i < N_NODES) ? counts[i] : 0;
    int sc = v;
    #pragma unroll
    for (int d = 1; d < 64; d <<= 1) {
        int up = __shfl_up(sc, d, 64);
        if (lane >= d) sc += up;
    }
    __shared__ int ws[SCAN_BLK / 64];
    if (lane == 63) ws[wid] = sc;
    __syncthreads();
    int waveOff = 0;
    #pragma unroll
    for (int w = 0; w < SCAN_BLK / 64; ++w)
        if (w < wid) waveOff += ws[w];
    int off = blockSums[blockIdx.x] + waveOff + (sc - v);
    if (i < N_NODES) {
        offsets[i] = off;
        cursor[i]  = off;
        if (i == N_NODES - 1) offsets[N_NODES] = off + v;
    }
}

// --- Kernel 3: bucket-fill edge sources (XCD-partitioned) -----------------
__global__ void __launch_bounds__(256)
mp_fill_kernel(const int* __restrict__ src,
               const int* __restrict__ tgt,
               int* __restrict__ cursor,
               int* __restrict__ edge_src) {
    const int xcd   = blockIdx.x & (NXCD - 1);
    const int chunk = blockIdx.x >> 3;
    const int lo = xcd * NODES_PER_XCD;
    const int hi = lo + NODES_PER_XCD;
    const int base = chunk * EDGES_PER_CHUNK;
    const int endc = base + EDGES_PER_CHUNK;
    for (int e = base + threadIdx.x; e < endc; e += 256) {
        int t = tgt[e];
        int s = src[e];
        if (t >= lo && t < hi) {
            int p = atomicAdd(&cursor[t], 1);
            edge_src[p] = s;
        }
    }
}

// --- Kernel 4: gather-mean. One wave per node, lane = feature. ------------
// Scalarized control: node id via readfirstlane so beg/end and the edge
// indices become s_loads; 8 independent x-row loads in flight per group.
__global__ void __launch_bounds__(256)
mp_gather_kernel(const float* __restrict__ x,
                 const int* __restrict__ offsets,
                 const int* __restrict__ edge_src,
                 float* __restrict__ out) {
    const int wid  = threadIdx.x >> 6;
    const int lane = threadIdx.x & 63;
    const int node = __builtin_amdgcn_readfirstlane(blockIdx.x * 4 + wid);
    if (node >= N_NODES) return;
    const int beg = offsets[node];
    const int end = offsets[node + 1];
    float acc = 0.f;
    for (int j = beg; j < end; j += 8) {
        int s0 = edge_src[j + 0];
        int s1 = edge_src[j + 1];
        int s2 = edge_src[j + 2];
        int s3 = edge_src[j + 3];
        int s4 = edge_src[j + 4];
        int s5 = edge_src[j + 5];
        int s6 = edge_src[j + 6];
        int s7 = edge_src[j + 7];
        const bool b1 = j + 1 < end, b2 = j + 2 < end, b3 = j + 3 < end;
        const bool b4 = j + 4 < end, b5 = j + 5 < end, b6 = j + 6 < end;
        const bool b7 = j + 7 < end;
        s1 = b1 ? s1 : s0;  s2 = b2 ? s2 : s0;  s3 = b3 ? s3 : s0;
        s4 = b4 ? s4 : s0;  s5 = b5 ? s5 : s0;  s6 = b6 ? s6 : s0;
        s7 = b7 ? s7 : s0;
        float a0 = x[(size_t)s0 * F_DIM + lane];
        float a1 = x[(size_t)s1 * F_DIM + lane];
        float a2 = x[(size_t)s2 * F_DIM + lane];
        float a3 = x[(size_t)s3 * F_DIM + lane];
        float a4 = x[(size_t)s4 * F_DIM + lane];
        float a5 = x[(size_t)s5 * F_DIM + lane];
        float a6 = x[(size_t)s6 * F_DIM + lane];
        float a7 = x[(size_t)s7 * F_DIM + lane];
        float t0 = a0 + (b1 ? a1 : 0.f);
        float t1 = (b2 ? a2 : 0.f) + (b3 ? a3 : 0.f);
        float t2 = (b4 ? a4 : 0.f) + (b5 ? a5 : 0.f);
        float t3 = (b6 ? a6 : 0.f) + (b7 ? a7 : 0.f);
        acc += (t0 + t1) + (t2 + t3);
    }
    const int deg = end - beg;
    const float inv = (deg > 0) ? 1.0f / (float)deg : 0.0f;
    out[(size_t)node * F_DIM + lane] = acc * inv;
}

// ===========================================================================
// Fallback (round-0 path) if workspace is too small — safety net only.
// ===========================================================================
__global__ void mp_count_simple(const int* __restrict__ tgt,
                                int* __restrict__ counts) {
    int e = blockIdx.x * blockDim.x + threadIdx.x;
    if (e < N_EDGES) atomicAdd(&counts[tgt[e]], 1);
}

__global__ void mp_scatter_kernel(const float* __restrict__ x,
                                  const int* __restrict__ src,
                                  const int* __restrict__ tgt,
                                  float* __restrict__ out) {
    int gid = blockIdx.x * blockDim.x + threadIdx.x;
    int e = gid >> 4;
    int q = gid & 15;
    if (e >= N_EDGES) return;
    int s = src[e];
    int t = tgt[e];
    const float4 v = *reinterpret_cast<const float4*>(x + (size_t)s * F_DIM + q * 4);
    float* o = out + (size_t)t * F_DIM + q * 4;
    unsafeAtomicAdd(o + 0, v.x);
    unsafeAtomicAdd(o + 1, v.y);
    unsafeAtomicAdd(o + 2, v.z);
    unsafeAtomicAdd(o + 3, v.w);
}

__global__ void mp_div_kernel(float* __restrict__ out,
                              const int* __restrict__ counts) {
    int gid = blockIdx.x * blockDim.x + threadIdx.x;
    int i = gid >> 4;
    int q = gid & 15;
    if (i >= N_NODES) return;
    float inv = 1.0f / fmaxf((float)counts[i], 1.0f);
    float4* o = reinterpret_cast<float4*>(out + (size_t)i * F_DIM + q * 4);
    float4 v = *o;
    v.x *= inv; v.y *= inv; v.z *= inv; v.w *= inv;
    *o = v;
}

extern "C" void kernel_launch(void* const* d_in, const int* in_sizes, int n_in,
                              void* d_out, int out_size, void* d_ws, size_t ws_size,
                              hipStream_t stream) {
    const float* x   = (const float*)d_in[0];
    const int*   src = (const int*)d_in[1];
    const int*   tgt = (const int*)d_in[2];
    float* out = (float*)d_out;

    const size_t need = (size_t)(N_NODES + 1 + N_NODES + N_NODES + N_EDGES
                                 + N_SCAN_BLOCKS) * sizeof(int);

    if (ws_size >= need) {
        int* offsets   = (int*)d_ws;                  // N+1
        int* cursor    = offsets + (N_NODES + 1);     // N
        int* counts    = cursor + N_NODES;            // N
        int* edge_src  = counts + N_NODES;            // E
        int* blockSums = edge_src + N_EDGES;          // NB

        hipMemsetAsync(counts, 0, (size_t)N_NODES * sizeof(int), stream);

        const int pblocks = FILL_CHUNKS * NXCD;       // 1024
        mp_count_kernel<<<pblocks, 256, 0, stream>>>(tgt, counts);
        mp_scan_blocksums<<<N_SCAN_BLOCKS, SCAN_BLK, 0, stream>>>(counts, blockSums);
        mp_scan_level1<<<1, 512, 0, stream>>>(blockSums);
        mp_scan_downsweep<<<N_SCAN_BLOCKS, SCAN_BLK, 0, stream>>>(counts, blockSums,
                                                                  offsets, cursor);
        mp_fill_kernel<<<pblocks, 256, 0, stream>>>(src, tgt, cursor, edge_src);
        int nblocks = (N_NODES + 3) / 4;              // 4 nodes (waves) per block
        mp_gather_kernel<<<nblocks, 256, 0, stream>>>(x, offsets, edge_src, out);
    } else {
        // Fallback: atomic scatter path (round-0).
        int* counts = (int*)d_ws;
        hipMemsetAsync(out, 0, (size_t)N_NODES * F_DIM * sizeof(float), stream);
        hipMemsetAsync(counts, 0, (size_t)N_NODES * sizeof(int), stream);
        int threads = 256;
        int eblocks = (N_EDGES + threads - 1) / threads;
        mp_count_simple<<<eblocks, threads, 0, stream>>>(tgt, counts);
        long long total = (long long)N_EDGES * 16;
        int sblocks = (int)((total + threads - 1) / threads);
        mp_scatter_kernel<<<sblocks, threads, 0, stream>>>(x, src, tgt, out);
        long long dtotal = (long long)N_NODES * 16;
        int dblocks = (int)((dtotal + threads - 1) / threads);
        mp_div_kernel<<<dblocks, threads, 0, stream>>>(out, counts);
    }
}

// Round 6
// 119.472 us; speedup vs baseline: 6.1444x; 1.0301x over previous
//
#include <hip/hip_runtime.h>

constexpr int N_NODES = 100000;
constexpr int N_EDGES = 800000;
constexpr int F_DIM   = 64;
constexpr int SCAN_BLK = 256;
constexpr int N_SCAN_BLOCKS = (N_NODES + SCAN_BLK - 1) / SCAN_BLK;   // 391

// XCD partitioning for the scatter phases.
constexpr int NXCD = 8;
constexpr int NODES_PER_XCD = N_NODES / NXCD;          // 12500
constexpr int FILL_CHUNKS = 128;                       // grid = 1024 blocks
constexpr int EDGES_PER_CHUNK = N_EDGES / FILL_CHUNKS; // 6250

// ===========================================================================
// CSR-build + gather implementation (no f32 atomics).
//   ws layout: offsets[N+1] | cursor[N] | counts[N] | edge_src[E] | blockSums[NB]
// NOTE: gather reads up to 7 ints past edge_src[E-1]; those land inside
// blockSums[] (valid memory) and are masked out of the sum.
//
// count/fill are XCD-partitioned: block b (heuristically on XCD b%8) filters
// edges to tgt-range [(b%8)*12500, +12500) so all atomics and scattered
// stores from one XCD hit a private region of cursor/counts/edge_src —
// avoids cross-XCD L2 line ping-pong (round-4 showed 16x write amplification).
// Mapping being wrong only costs speed, not correctness.
//
// Round 6: hipMemsetAsync(counts) was dispatched by the runtime as a
// tiny-grid fillBufferAligned taking ~40us (latency-bound, 8% occupancy).
// Replaced with a custom full-occupancy zero kernel (~2us).
// ===========================================================================

// --- Kernel 0: zero the counts array (replaces runtime memset) ------------
__global__ void __launch_bounds__(256)
mp_zero_kernel(int* __restrict__ counts) {
    int i = blockIdx.x * 256 + threadIdx.x;
    if (i < N_NODES) counts[i] = 0;
}

// --- Kernel 1: in-degree counts (XCD-partitioned) -------------------------
__global__ void __launch_bounds__(256)
mp_count_kernel(const int* __restrict__ tgt, int* __restrict__ counts) {
    const int xcd   = blockIdx.x & (NXCD - 1);
    const int chunk = blockIdx.x >> 3;
    const int lo = xcd * NODES_PER_XCD;
    const int hi = lo + NODES_PER_XCD;
    const int base = chunk * EDGES_PER_CHUNK;
    const int endc = base + EDGES_PER_CHUNK;
    for (int e = base + threadIdx.x; e < endc; e += 256) {
        int t = tgt[e];
        if (t >= lo && t < hi) atomicAdd(&counts[t], 1);
    }
}

// --- Kernel 2a: per-block sums of counts ----------------------------------
__global__ void __launch_bounds__(SCAN_BLK)
mp_scan_blocksums(const int* __restrict__ counts, int* __restrict__ blockSums) {
    const int tid  = threadIdx.x;
    const int lane = tid & 63;
    const int wid  = tid >> 6;
    int i = blockIdx.x * SCAN_BLK + tid;
    int v = (i < N_NODES) ? counts[i] : 0;
    #pragma unroll
    for (int d = 32; d > 0; d >>= 1) v += __shfl_down(v, d, 64);
    __shared__ int ws[SCAN_BLK / 64];
    if (lane == 0) ws[wid] = v;
    __syncthreads();
    if (tid == 0) blockSums[blockIdx.x] = ws[0] + ws[1] + ws[2] + ws[3];
}

// --- Kernel 2b: exclusive scan of the 391 block sums (one block) ----------
__global__ void __launch_bounds__(512)
mp_scan_level1(int* __restrict__ blockSums) {
    const int tid  = threadIdx.x;
    const int lane = tid & 63;
    const int wid  = tid >> 6;
    int v = (tid < N_SCAN_BLOCKS) ? blockSums[tid] : 0;
    int sc = v;
    #pragma unroll
    for (int d = 1; d < 64; d <<= 1) {
        int up = __shfl_up(sc, d, 64);
        if (lane >= d) sc += up;
    }
    __shared__ int ws[8];
    if (lane == 63) ws[wid] = sc;
    __syncthreads();
    if (tid < 8) {
        int w = ws[tid];
        int scw = w;
        #pragma unroll
        for (int d = 1; d < 8; d <<= 1) {
            int up = __shfl_up(scw, d, 8);
            if (tid >= d) scw += up;
        }
        ws[tid] = scw - w;          // exclusive wave offset
    }
    __syncthreads();
    if (tid < N_SCAN_BLOCKS) blockSums[tid] = ws[wid] + (sc - v);
}

// --- Kernel 2c: downsweep — write offsets AND cursor ----------------------
__global__ void __launch_bounds__(SCAN_BLK)
mp_scan_downsweep(const int* __restrict__ counts,
                  const int* __restrict__ blockSums,
                  int* __restrict__ offsets,
                  int* __restrict__ cursor) {
    const int tid  = threadIdx.x;
    const int lane = tid & 63;
    const int wid  = tid >> 6;
    int i = blockIdx.x * SCAN_BLK + tid;
    int v = (i < N_NODES) ? counts[i] : 0;
    int sc = v;
    #pragma unroll
    for (int d = 1; d < 64; d <<= 1) {
        int up = __shfl_up(sc, d, 64);
        if (lane >= d) sc += up;
    }
    __shared__ int ws[SCAN_BLK / 64];
    if (lane == 63) ws[wid] = sc;
    __syncthreads();
    int waveOff = 0;
    #pragma unroll
    for (int w = 0; w < SCAN_BLK / 64; ++w)
        if (w < wid) waveOff += ws[w];
    int off = blockSums[blockIdx.x] + waveOff + (sc - v);
    if (i < N_NODES) {
        offsets[i] = off;
        cursor[i]  = off;
        if (i == N_NODES - 1) offsets[N_NODES] = off + v;
    }
}

// --- Kernel 3: bucket-fill edge sources (XCD-partitioned) -----------------
__global__ void __launch_bounds__(256)
mp_fill_kernel(const int* __restrict__ src,
               const int* __restrict__ tgt,
               int* __restrict__ cursor,
               int* __restrict__ edge_src) {
    const int xcd   = blockIdx.x & (NXCD - 1);
    const int chunk = blockIdx.x >> 3;
    const int lo = xcd * NODES_PER_XCD;
    const int hi = lo + NODES_PER_XCD;
    const int base = chunk * EDGES_PER_CHUNK;
    const int endc = base + EDGES_PER_CHUNK;
    for (int e = base + threadIdx.x; e < endc; e += 256) {
        int t = tgt[e];
        int s = src[e];
        if (t >= lo && t < hi) {
            int p = atomicAdd(&cursor[t], 1);
            edge_src[p] = s;
        }
    }
}

// --- Kernel 4: gather-mean. One wave per node, lane = feature. ------------
// Scalarized control: node id via readfirstlane so beg/end and the edge
// indices become s_loads; 8 independent x-row loads in flight per group.
__global__ void __launch_bounds__(256)
mp_gather_kernel(const float* __restrict__ x,
                 const int* __restrict__ offsets,
                 const int* __restrict__ edge_src,
                 float* __restrict__ out) {
    const int wid  = threadIdx.x >> 6;
    const int lane = threadIdx.x & 63;
    const int node = __builtin_amdgcn_readfirstlane(blockIdx.x * 4 + wid);
    if (node >= N_NODES) return;
    const int beg = offsets[node];
    const int end = offsets[node + 1];
    float acc = 0.f;
    for (int j = beg; j < end; j += 8) {
        int s0 = edge_src[j + 0];
        int s1 = edge_src[j + 1];
        int s2 = edge_src[j + 2];
        int s3 = edge_src[j + 3];
        int s4 = edge_src[j + 4];
        int s5 = edge_src[j + 5];
        int s6 = edge_src[j + 6];
        int s7 = edge_src[j + 7];
        const bool b1 = j + 1 < end, b2 = j + 2 < end, b3 = j + 3 < end;
        const bool b4 = j + 4 < end, b5 = j + 5 < end, b6 = j + 6 < end;
        const bool b7 = j + 7 < end;
        s1 = b1 ? s1 : s0;  s2 = b2 ? s2 : s0;  s3 = b3 ? s3 : s0;
        s4 = b4 ? s4 : s0;  s5 = b5 ? s5 : s0;  s6 = b6 ? s6 : s0;
        s7 = b7 ? s7 : s0;
        float a0 = x[(size_t)s0 * F_DIM + lane];
        float a1 = x[(size_t)s1 * F_DIM + lane];
        float a2 = x[(size_t)s2 * F_DIM + lane];
        float a3 = x[(size_t)s3 * F_DIM + lane];
        float a4 = x[(size_t)s4 * F_DIM + lane];
        float a5 = x[(size_t)s5 * F_DIM + lane];
        float a6 = x[(size_t)s6 * F_DIM + lane];
        float a7 = x[(size_t)s7 * F_DIM + lane];
        float t0 = a0 + (b1 ? a1 : 0.f);
        float t1 = (b2 ? a2 : 0.f) + (b3 ? a3 : 0.f);
        float t2 = (b4 ? a4 : 0.f) + (b5 ? a5 : 0.f);
        float t3 = (b6 ? a6 : 0.f) + (b7 ? a7 : 0.f);
        acc += (t0 + t1) + (t2 + t3);
    }
    const int deg = end - beg;
    const float inv = (deg > 0) ? 1.0f / (float)deg : 0.0f;
    out[(size_t)node * F_DIM + lane] = acc * inv;
}

// ===========================================================================
// Fallback (round-0 path) if workspace is too small — safety net only.
// ===========================================================================
__global__ void mp_count_simple(const int* __restrict__ tgt,
                                int* __restrict__ counts) {
    int e = blockIdx.x * blockDim.x + threadIdx.x;
    if (e < N_EDGES) atomicAdd(&counts[tgt[e]], 1);
}

__global__ void mp_scatter_kernel(const float* __restrict__ x,
                                  const int* __restrict__ src,
                                  const int* __restrict__ tgt,
                                  float* __restrict__ out) {
    int gid = blockIdx.x * blockDim.x + threadIdx.x;
    int e = gid >> 4;
    int q = gid & 15;
    if (e >= N_EDGES) return;
    int s = src[e];
    int t = tgt[e];
    const float4 v = *reinterpret_cast<const float4*>(x + (size_t)s * F_DIM + q * 4);
    float* o = out + (size_t)t * F_DIM + q * 4;
    unsafeAtomicAdd(o + 0, v.x);
    unsafeAtomicAdd(o + 1, v.y);
    unsafeAtomicAdd(o + 2, v.z);
    unsafeAtomicAdd(o + 3, v.w);
}

__global__ void mp_div_kernel(float* __restrict__ out,
                              const int* __restrict__ counts) {
    int gid = blockIdx.x * blockDim.x + threadIdx.x;
    int i = gid >> 4;
    int q = gid & 15;
    if (i >= N_NODES) return;
    float inv = 1.0f / fmaxf((float)counts[i], 1.0f);
    float4* o = reinterpret_cast<float4*>(out + (size_t)i * F_DIM + q * 4);
    float4 v = *o;
    v.x *= inv; v.y *= inv; v.z *= inv; v.w *= inv;
    *o = v;
}

extern "C" void kernel_launch(void* const* d_in, const int* in_sizes, int n_in,
                              void* d_out, int out_size, void* d_ws, size_t ws_size,
                              hipStream_t stream) {
    const float* x   = (const float*)d_in[0];
    const int*   src = (const int*)d_in[1];
    const int*   tgt = (const int*)d_in[2];
    float* out = (float*)d_out;

    const size_t need = (size_t)(N_NODES + 1 + N_NODES + N_NODES + N_EDGES
                                 + N_SCAN_BLOCKS) * sizeof(int);

    if (ws_size >= need) {
        int* offsets   = (int*)d_ws;                  // N+1
        int* cursor    = offsets + (N_NODES + 1);     // N
        int* counts    = cursor + N_NODES;            // N
        int* edge_src  = counts + N_NODES;            // E
        int* blockSums = edge_src + N_EDGES;          // NB

        mp_zero_kernel<<<N_SCAN_BLOCKS, 256, 0, stream>>>(counts);

        const int pblocks = FILL_CHUNKS * NXCD;       // 1024
        mp_count_kernel<<<pblocks, 256, 0, stream>>>(tgt, counts);
        mp_scan_blocksums<<<N_SCAN_BLOCKS, SCAN_BLK, 0, stream>>>(counts, blockSums);
        mp_scan_level1<<<1, 512, 0, stream>>>(blockSums);
        mp_scan_downsweep<<<N_SCAN_BLOCKS, SCAN_BLK, 0, stream>>>(counts, blockSums,
                                                                  offsets, cursor);
        mp_fill_kernel<<<pblocks, 256, 0, stream>>>(src, tgt, cursor, edge_src);
        int nblocks = (N_NODES + 3) / 4;              // 4 nodes (waves) per block
        mp_gather_kernel<<<nblocks, 256, 0, stream>>>(x, offsets, edge_src, out);
    } else {
        // Fallback: atomic scatter path (round-0).
        int* counts = (int*)d_ws;
        hipMemsetAsync(out, 0, (size_t)N_NODES * F_DIM * sizeof(float), stream);
        hipMemsetAsync(counts, 0, (size_t)N_NODES * sizeof(int), stream);
        int threads = 256;
        int eblocks = (N_EDGES + threads - 1) / threads;
        mp_count_simple<<<eblocks, threads, 0, stream>>>(tgt, counts);
        long long total = (long long)N_EDGES * 16;
        int sblocks = (int)((total + threads - 1) / threads);
        mp_scatter_kernel<<<sblocks, threads, 0, stream>>>(x, src, tgt, out);
        long long dtotal = (long long)N_NODES * 16;
        int dblocks = (int)((dtotal + threads - 1) / threads);
        mp_div_kernel<<<dblocks, threads, 0, stream>>>(out, counts);
    }
}